// Round 7
// baseline (753.201 us; speedup 1.0000x reference)
//
#include <hip/hip_runtime.h>
#include <hip/hip_bf16.h>

// Problem dims
#define BB 64
#define TT 168
#define NN 64
#define FF 17
#define HID 128
#define GATES 512   // 4*HID
#define NLAYERS 4
#define NROWS (BB*TT)   // 10752

// LSTM pipeline chunking
#define CH 8
#define NCHUNK (TT/CH)  // 21

// Workspace layout (float offsets)
#define WS_W1SRC 0
#define WS_W1DST 32
#define WS_W2SRC 64
#define WS_W2DST 192
#define WS_BSUM  320                    // 4*512 -> ends 2368
#define WS_WD    2560                   // 17 (pad 32): W1 @ (W2 @ a2dst)
#define WS_WSV   2592                   // 17 (pad 32): W1 @ (W2 @ a2src)
#define WS_W12   2624                   // 17*128 = 2176: W1 @ W2
#define WS_WXG0T 4800                   // 512*20 (17 used): (W12 @ Wih0^T)^T rows -> ends 15040
#define WS_ADJB  15104                  // 64 u64 adjacency bitmasks (128 floats) -> ends 15232
#define WS_FLAGS 16000                  // 256 ints: per-(layer,batch) progress counters
#define WS_XG    1395712                // NROWS*512 = 5505024 (layer-0 gates from GAT)
#define WS_HSEQ0 6900736                // 4 buffers of NROWS*HID
#define HSEQ_SZ  1376256

// LDS-only barrier: s_waitcnt lgkmcnt(0) + raw s_barrier (no vmcnt drain).
__device__ __forceinline__ void lds_barrier() {
    __asm__ volatile("" ::: "memory");
    __builtin_amdgcn_s_waitcnt(0xc07f);
    __builtin_amdgcn_s_barrier();
    __asm__ volatile("" ::: "memory");
}

__device__ __forceinline__ float fsig(float x) {
    return __builtin_amdgcn_rcpf(1.f + __expf(-x));
}
__device__ __forceinline__ float ftanh(float x) {
    float e = __expf(2.f * x);
    return 1.f - 2.f * __builtin_amdgcn_rcpf(e + 1.f);
}

// ---------------- prep1: attention projection vectors + bias sums + adj bitmasks + flag reset ----------------
__global__ void prep1(const float* __restrict__ W1, const float* __restrict__ a1,
                      const float* __restrict__ W2, const float* __restrict__ a2,
                      const float* __restrict__ bih, const float* __restrict__ bhh,
                      const int* __restrict__ adj, float* __restrict__ ws) {
    int tid = threadIdx.x;
    if (tid < 34) {
        int f = tid % FF, half = tid / FF;
        float acc = 0.f;
        for (int o = 0; o < HID; o++) acc += W1[f*HID + o] * a1[half*HID + o];
        ws[(half ? WS_W1DST : WS_W1SRC) + f] = acc;
    }
    {
        int k = tid & 127, half = tid >> 7;
        float acc = 0.f;
        for (int o = 0; o < HID; o++) acc += W2[k*HID + o] * a2[half*HID + o];
        ws[(half ? WS_W2DST : WS_W2SRC) + k] = acc;
    }
    for (int idx = tid; idx < NLAYERS*GATES; idx += 256) ws[WS_BSUM + idx] = bih[idx] + bhh[idx];
    // adjacency bitmasks (with self-loop), computed once for all 10752 GAT blocks
    if (tid < 64) {
        unsigned long long m = 1ull << tid;
        const int* ar = adj + tid*64;
        for (int j = 0; j < 64; j++) if (ar[j] > 0) m |= (1ull << j);
        ((unsigned long long*)(ws + WS_ADJB))[tid] = m;
    }
    // reset pipeline flags (agent-scope so lstm_pipe's coherent loads see zeros)
    __hip_atomic_store((int*)(ws + WS_FLAGS) + tid, 0,
                       __ATOMIC_RELAXED, __HIP_MEMORY_SCOPE_AGENT);
}

// ---------------- prep2: W12 = W1 @ W2 (17 x 128) ----------------
__global__ void prep2(const float* __restrict__ W1, const float* __restrict__ W2,
                      float* __restrict__ ws) {
    int f = blockIdx.x, o = threadIdx.x;
    float acc = 0.f;
    for (int k = 0; k < HID; k++) acc += W1[f*HID + k] * W2[k*HID + o];
    ws[WS_W12 + f*HID + o] = acc;
}

// ---------------- prep3: WD/WSV (17 each) + WXG0T (512 x 17, stride 20) ----------------
__global__ void prep3(const float* __restrict__ W1, const float* __restrict__ Wih0,
                      float* __restrict__ ws) {
    int idx = blockIdx.x * 256 + threadIdx.x;
    if (idx < 17) {
        int f = idx;
        float acc = 0.f;
        for (int k = 0; k < HID; k++) acc += W1[f*HID + k] * ws[WS_W2DST + k];
        ws[WS_WD + f] = acc;
    } else if (idx < 34) {
        int f = idx - 17;
        float acc = 0.f;
        for (int k = 0; k < HID; k++) acc += W1[f*HID + k] * ws[WS_W2SRC + k];
        ws[WS_WSV + f] = acc;
    } else if (idx < 34 + GATES*FF) {
        int e = idx - 34;
        int j = e % GATES, f = e / GATES;   // f < 17
        float acc = 0.f;
        for (int o = 0; o < HID; o++) acc += ws[WS_W12 + f*HID + o] * Wih0[j*HID + o];
        ws[WS_WXG0T + j*20 + f] = acc;
    }
}

// ---------------- K1: fused GAT1 + GAT2(site) -> Xg layer-0 directly ----------------
struct __align__(16) GatSmem {
    float attn[64*68];       // P2 writes rows (stride 68), P3 reads
    float xsT[FF*64];        // [f][n]
    float xbarT[FF*68];      // [f][i], stride 68
    float src1[64], dst1[64], rinv[64], att2[64];
    float xbar2[20];
    float part_x[FF*8];      // P5a partials
    unsigned long long adjbits[64];
};
// ~28.5 KB -> 5 blocks/CU

__global__ __launch_bounds__(256) void gat_fused(const float* __restrict__ x, const int* __restrict__ adj,
                                                 const float* __restrict__ ws,
                                                 float* __restrict__ Xg, const int* __restrict__ site_ptr) {
    __shared__ GatSmem sm;
    const int tid = threadIdx.x;
    const int tt = blockIdx.x, bb = blockIdx.y;
    const int site = site_ptr[0];
    const int r = bb*TT + tt;
    const float* xblk = x + (size_t)r * (NN*FF);

    // P0: x transposed into LDS, adjacency bitmasks from prep1
    for (int idx = tid; idx < NN*FF; idx += 256) {
        int n = idx / FF, f = idx % FF;
        sm.xsT[f*64 + n] = xblk[idx];
    }
    if (tid < 64) sm.adjbits[tid] = ((const unsigned long long*)(ws + WS_ADJB))[tid];
    lds_barrier();

    // P1: src1/dst1 = x . (W1 @ a1-halves)
    if (tid < 128) {
        int n = tid & 63, half = tid >> 6;
        const float* wv = ws + (half ? WS_W1DST : WS_W1SRC);
        float acc = 0.f;
        #pragma unroll
        for (int f = 0; f < FF; f++) acc += sm.xsT[f*64 + n] * wv[f];
        if (half) sm.dst1[n] = acc; else sm.src1[n] = acc;
    }
    lds_barrier();

    // P2: attention logits -> exp -> attn rows
    {
        int q = tid & 3, i = tid >> 2;
        unsigned long long ab = sm.adjbits[i];
        float si = sm.src1[i];
        float v[16];
        float vmax = -1e30f;
        #pragma unroll
        for (int u = 0; u < 16; u++) {
            int jj = q*16 + u;
            float e = si + sm.dst1[jj];
            float lv = fmaxf(e, 0.2f*e);
            lv = ((ab >> jj) & 1ull) ? lv : -1e9f;
            v[u] = lv;
            vmax = fmaxf(vmax, lv);
        }
        vmax = fmaxf(vmax, __shfl_xor(vmax, 1, 4));
        vmax = fmaxf(vmax, __shfl_xor(vmax, 2, 4));
        float s = 0.f;
        float* arow = &sm.attn[i*68];
        #pragma unroll
        for (int w = 0; w < 4; w++) {
            float4 pv;
            pv.x = __expf(v[w*4+0] - vmax);
            pv.y = __expf(v[w*4+1] - vmax);
            pv.z = __expf(v[w*4+2] - vmax);
            pv.w = __expf(v[w*4+3] - vmax);
            s += (pv.x + pv.y) + (pv.z + pv.w);
            *(float4*)(arow + q*16 + w*4) = pv;
        }
        s += __shfl_xor(s, 1, 4);
        s += __shfl_xor(s, 2, 4);
        if (q == 0) sm.rinv[i] = 1.f / s;
    }
    lds_barrier();

    // P3: xbarT[f][i] = (P @ X)[i][f] * rinv
    {
        int i = tid & 63, q = tid >> 6;
        const float* arow = &sm.attn[i*68];
        float acc[5] = {0.f,0.f,0.f,0.f,0.f};
        const int nf = (q == 0) ? 5 : 4;
        for (int j4 = 0; j4 < 16; j4++) {
            float4 a4 = *(const float4*)(arow + j4*4);
            #pragma unroll
            for (int u = 0; u < 5; u++) {
                if (u < nf) {
                    int f = q + 4*u;
                    float4 x4 = *(const float4*)(&sm.xsT[f*64 + j4*4]);
                    acc[u] += a4.x*x4.x + a4.y*x4.y + a4.z*x4.z + a4.w*x4.w;
                }
            }
        }
        float ri = sm.rinv[i];
        #pragma unroll
        for (int u = 0; u < 5; u++) {
            if (u < nf) sm.xbarT[(q + 4*u)*68 + i] = acc[u] * ri;
        }
    }
    lds_barrier();

    // P4' (wave 0): dst2[j] = xbar[j].WD ; src2 = xbar[site].WSV ; softmax -> att2
    if (tid < 64) {
        int jj = tid;
        float d = 0.f, sp = 0.f;
        #pragma unroll
        for (int f = 0; f < FF; f++) {
            float xv = sm.xbarT[f*68 + jj];
            float xs = sm.xbarT[f*68 + site];
            d  += xv * ws[WS_WD + f];
            sp += xs * ws[WS_WSV + f];
        }
        unsigned long long ab = sm.adjbits[site];
        float e = sp + d;
        float lv = fmaxf(e, 0.2f*e);
        lv = ((ab >> jj) & 1ull) ? lv : -1e9f;
        float m = lv;
        #pragma unroll
        for (int dd = 1; dd < 64; dd <<= 1) m = fmaxf(m, __shfl_xor(m, dd));
        float p = __expf(lv - m);
        float s = p;
        #pragma unroll
        for (int dd = 1; dd < 64; dd <<= 1) s += __shfl_xor(s, dd);
        sm.att2[jj] = p / s;
    }
    lds_barrier();

    // P5a: xbar2 partials
    if (tid < FF*8) {
        int f = tid >> 3, c = tid & 7;
        float p = 0.f;
        #pragma unroll
        for (int u = 0; u < 8; u++) {
            int i = c*8 + u;
            p += sm.att2[i] * sm.xbarT[f*68 + i];
        }
        sm.part_x[f*8 + c] = p;
    }
    lds_barrier();

    // P5b: reduce xbar2
    if (tid < FF) {
        float s = 0.f;
        #pragma unroll
        for (int c = 0; c < 8; c++) s += sm.part_x[tid*8 + c];
        sm.xbar2[tid] = s;
    }
    lds_barrier();

    // P6': Xg0[r][j] = xbar2 . WXG0T[j] + bsum0[j]
    {
        float xb[FF];
        #pragma unroll
        for (int f = 0; f < FF; f++) xb[f] = sm.xbar2[f];
        #pragma unroll
        for (int half = 0; half < 2; half++) {
            int j = tid + half*256;
            const float4* wp = (const float4*)(ws + WS_WXG0T + j*20);
            float4 w0 = wp[0], w1 = wp[1], w2 = wp[2], w3 = wp[3];
            float wlast = ws[WS_WXG0T + j*20 + 16];
            float acc = ws[WS_BSUM + j];
            acc += w0.x*xb[0] + w0.y*xb[1] + w0.z*xb[2] + w0.w*xb[3];
            acc += w1.x*xb[4] + w1.y*xb[5] + w1.z*xb[6] + w1.w*xb[7];
            acc += w2.x*xb[8] + w2.y*xb[9] + w2.z*xb[10] + w2.w*xb[11];
            acc += w3.x*xb[12] + w3.y*xb[13] + w3.z*xb[14] + w3.w*xb[15];
            acc += wlast*xb[16];
            Xg[(size_t)r*GATES + j] = acc;
        }
    }
}

// ---------------- K2: all-layer pipelined recurrence, 256 threads/block ----------------
// Grid: (BB, NLAYERS) = 256 blocks of 256 threads (4 waves), 1 block/CU.
//
// WHY 256 threads: 512-thread blocks are register-capped at ~116 VGPRs by the
// allocator (measured r2/r4/r5/r6 — launch_bounds, waves_per_eu, LDS-forcing
// all failed to move it), so the 128 Whh floats/thread could never be
// loop-resident and were restreamed from L2 every step (8 MB/XCD/step ~ 1.9us
// = the wall). 256-thread kernels demonstrably allocate more (m97: 164; m08:
// no-spill to 450). Here each thread holds 4 gates x 64 k = 256 Whh floats in
// registers (~340 VGPR total demand); waves_per_eu(1,1) + >80KB LDS force
// 1 wave/EU = 512-reg budget.
//
// h routing: a thread needs h[kc2*64..+64) but its wave's owners hold only 32
// values -> h goes through a 1KB double-buffered LDS hbuf (broadcast reads,
// conflict-free), costing a second barrier per step:
//   [xgc, A(matvec from hbuf[t&1]), part write] bar1 [B2 -> hbuf[(t+1)&1], B1] bar2
// B1 (input GEMM for chunk c+1): 2 gates/thread (tid, 256+tid), weights
// prefetched one slice ahead in registers. Flags relaxed + vmcnt(0) drain
// (r2-measured-fastest protocol).
__global__ __launch_bounds__(256)
__attribute__((amdgpu_waves_per_eu(1, 1)))
void lstm_pipe(const float* __restrict__ Xg0,
               const float* __restrict__ Wih,
               const float* __restrict__ Whh,
               float* __restrict__ ws) {
    const int b = blockIdx.x;
    const int l = blockIdx.y;
    const int tid = threadIdx.x;
    const int lane = tid & 63;
    const int kc2 = tid >> 7;                    // 0..1: k-half
    const int jj = tid & 127;                    // gate slot
    const int o = (tid >> 6)*32 + (lane & 31);   // owned h index (blane threads), unique 0..127
    const bool blane = (lane < 32);

    __shared__ __align__(16) float part[2][2][128][4];   // 8 KB
    __shared__ __align__(16) float xg[2][CH*GATES];      // 32 KB
    __shared__ __align__(16) float xs[2][CH*HID];        // 8 KB
    __shared__ __align__(16) float hbuf[2][HID];         // 1 KB
    __shared__ __align__(16) float lds_pad[9216];        // 36 KB: occupancy forcing (runtime-dead)

    int* flags = (int*)(ws + WS_FLAGS);

    // Runtime-never-true guard keeps lds_pad allocated (flags[255] is only ever 0).
    if (__hip_atomic_load(&flags[255], __ATOMIC_RELAXED, __HIP_MEMORY_SCOPE_AGENT) == 0x7fffffff) {
        lds_pad[tid] = (float)tid;
        __builtin_amdgcn_s_waitcnt(0xc07f);
        ((float*)ws)[tid] = lds_pad[tid ^ 1];
    }

    // Whh fragment -> registers: 4 gates x 64 k = 64 float4
    float4 w4[4][16];
    {
        const float* Whh_l = Whh + (size_t)l*GATES*HID;
        #pragma unroll
        for (int u = 0; u < 4; u++) {
            const float4* p = (const float4*)(Whh_l + (size_t)(u*128 + jj)*HID + kc2*64);
            #pragma unroll
            for (int k4 = 0; k4 < 16; k4++) w4[u][k4] = p[k4];
        }
    }

    const float* xg_g  = Xg0 + (size_t)b*TT*GATES;
    float*       hout  = ws + WS_HSEQ0 + (size_t)l*HSEQ_SZ + (size_t)b*TT*HID;
    const float* hprev = (l > 0) ? (ws + WS_HSEQ0 + (size_t)(l-1)*HSEQ_SZ + (size_t)b*TT*HID)
                                 : ws;
    const float* Wih_l = Wih + (size_t)l*GATES*HID;
    const float  bsA = ws[WS_BSUM + l*GATES + tid];
    const float  bsB = ws[WS_BSUM + l*GATES + 256 + tid];
    const float4* wrA = (const float4*)(Wih_l + (size_t)tid*HID);
    const float4* wrB = (const float4*)(Wih_l + (size_t)(256 + tid)*HID);

    float h_own = 0.f, c_own = 0.f;
    float4 pf0 = {0,0,0,0}, pf1 = {0,0,0,0}, pf2 = {0,0,0,0}, pf3 = {0,0,0,0};
    int buf = 0;

    float accA[CH], accB[CH];                        // next-chunk ingemm accumulators (l>0)
    float4 wva0, wva1, wva2, wva3;                   // current-slice Wih weights, row A
    float4 wvb0, wvb1, wvb2, wvb3;                   // row B

    if (blane) hbuf[0][o] = 0.f;                     // h(-1) = 0

    if (l == 0) {
        // stage chunk 0 of Xg into xg[0] (16 KB, 4 float4/thread)
        const float4* g4 = (const float4*)xg_g;
        float4* d = (float4*)xg[0];
        #pragma unroll
        for (int q = 0; q < 4; q++) d[q*256 + tid] = g4[q*256 + tid];
        lds_barrier();
    } else {
        // prologue: wait chunk 0, stage xs[0], serial ingemm -> xg[0]
        if (tid == 0) {
            int* flg = &flags[(l-1)*BB + b];
            while (__hip_atomic_load(flg, __ATOMIC_RELAXED, __HIP_MEMORY_SCOPE_AGENT) < CH)
                __builtin_amdgcn_s_sleep(8);
        }
        lds_barrier();
        #pragma unroll
        for (int q = 0; q < 4; q++) {
            int idx = q*256 + tid;
            xs[0][idx] = __hip_atomic_load(&hprev[idx],
                                           __ATOMIC_RELAXED, __HIP_MEMORY_SCOPE_AGENT);
        }
        lds_barrier();
        float aA[CH], aB[CH];
        #pragma unroll
        for (int t = 0; t < CH; t++) { aA[t] = bsA; aB[t] = bsB; }
        for (int s = 0; s < CH; s++) {
            float4 qa0 = wrA[s*4+0], qa1 = wrA[s*4+1], qa2 = wrA[s*4+2], qa3 = wrA[s*4+3];
            float4 qb0 = wrB[s*4+0], qb1 = wrB[s*4+1], qb2 = wrB[s*4+2], qb3 = wrB[s*4+3];
            #pragma unroll
            for (int t2 = 0; t2 < CH; t2++) {
                const float4* xp = (const float4*)(&xs[0][t2*HID + s*16]);
                float4 x0 = xp[0], x1 = xp[1], x2 = xp[2], x3 = xp[3];
                aA[t2] += qa0.x*x0.x + qa0.y*x0.y + qa0.z*x0.z + qa0.w*x0.w
                        + qa1.x*x1.x + qa1.y*x1.y + qa1.z*x1.z + qa1.w*x1.w
                        + qa2.x*x2.x + qa2.y*x2.y + qa2.z*x2.z + qa2.w*x2.w
                        + qa3.x*x3.x + qa3.y*x3.y + qa3.z*x3.z + qa3.w*x3.w;
                aB[t2] += qb0.x*x0.x + qb0.y*x0.y + qb0.z*x0.z + qb0.w*x0.w
                        + qb1.x*x1.x + qb1.y*x1.y + qb1.z*x1.z + qb1.w*x1.w
                        + qb2.x*x2.x + qb2.y*x2.y + qb2.z*x2.z + qb2.w*x2.w
                        + qb3.x*x3.x + qb3.y*x3.y + qb3.z*x3.z + qb3.w*x3.w;
            }
        }
        #pragma unroll
        for (int t = 0; t < CH; t++) {
            xg[0][t*GATES + tid]       = aA[t];
            xg[0][t*GATES + 256 + tid] = aB[t];
        }
        // init slice-0 weights + accumulators for the interleaved pipeline
        wva0 = wrA[0]; wva1 = wrA[1]; wva2 = wrA[2]; wva3 = wrA[3];
        wvb0 = wrB[0]; wvb1 = wrB[1]; wvb2 = wrB[2]; wvb3 = wrB[3];
        #pragma unroll
        for (int t = 0; t < CH; t++) { accA[t] = bsA; accB[t] = bsB; }
        lds_barrier();
    }

    for (int c = 0; c < NCHUNK; c++) {
        const bool have_next = (c + 1 < NCHUNK);

        if (l == 0) {
            if (have_next) {
                const float4* g4 = (const float4*)(xg_g + (size_t)(c+1)*CH*GATES);
                pf0 = g4[0*256 + tid]; pf1 = g4[1*256 + tid];
                pf2 = g4[2*256 + tid]; pf3 = g4[3*256 + tid];
            }
        } else if (have_next) {
            // wait for producer chunk c+1; stage it into xs[(c+1)&1]
            if (tid == 0) {
                int* flg = &flags[(l-1)*BB + b];
                const int need = (c + 2)*CH;
                while (__hip_atomic_load(flg, __ATOMIC_RELAXED, __HIP_MEMORY_SCOPE_AGENT) < need)
                    __builtin_amdgcn_s_sleep(8);
            }
            lds_barrier();
            #pragma unroll
            for (int q = 0; q < 4; q++) {
                int idx = q*256 + tid;
                xs[(c+1)&1][idx] = __hip_atomic_load(&hprev[(size_t)(c+1)*CH*HID + idx],
                                                     __ATOMIC_RELAXED, __HIP_MEMORY_SCOPE_AGENT);
            }
            // ds_writes drained by step-0's bar1 (lgkmcnt(0) before s_barrier)
        }

        const float* xgbuf = (l == 0) ? xg[buf] : xg[c & 1];
        const float* xsn = xs[(c+1)&1];
        float* xgn = xg[(c+1)&1];

        for (int tc = 0; tc < CH; tc++) {
            const int t = c*CH + tc;
            float xgc0, xgc1, xgc2, xgc3;
            if (blane) {
                xgc0 = xgbuf[tc*GATES + 0*HID + o];
                xgc1 = xgbuf[tc*GATES + 1*HID + o];
                xgc2 = xgbuf[tc*GATES + 2*HID + o];
                xgc3 = xgbuf[tc*GATES + 3*HID + o];
            }
            // A: Whh partial matvec from register-resident weights + hbuf broadcast
            float a0 = 0.f, a1 = 0.f, a2 = 0.f, a3 = 0.f;
            {
                const float4* hb = (const float4*)(&hbuf[t & 1][kc2*64]);
                #pragma unroll
                for (int k4 = 0; k4 < 16; k4++) {
                    float4 h4 = hb[k4];
                    a0 += w4[0][k4].x*h4.x + w4[0][k4].y*h4.y + w4[0][k4].z*h4.z + w4[0][k4].w*h4.w;
                    a1 += w4[1][k4].x*h4.x + w4[1][k4].y*h4.y + w4[1][k4].z*h4.z + w4[1][k4].w*h4.w;
                    a2 += w4[2][k4].x*h4.x + w4[2][k4].y*h4.y + w4[2][k4].z*h4.z + w4[2][k4].w*h4.w;
                    a3 += w4[3][k4].x*h4.x + w4[3][k4].y*h4.y + w4[3][k4].z*h4.z + w4[3][k4].w*h4.w;
                }
            }
            float4 st = {a0, a1, a2, a3};
            *(float4*)(&part[t & 1][kc2][jj][0]) = st;

            lds_barrier();   // bar1: part ready

            // B2: owners compute gates -> h_own; publish h into hbuf[(t+1)&1]
            if (blane) {
                float4 p0 = *(const float4*)(&part[t & 1][0][o][0]);
                float4 p1 = *(const float4*)(&part[t & 1][1][o][0]);
                float gi = xgc0 + p0.x + p1.x;
                float gf = xgc1 + p0.y + p1.y;
                float gg = xgc2 + p0.z + p1.z;
                float go = xgc3 + p0.w + p1.w;
                float si = fsig(gi), sf = fsig(gf), so = fsig(go);
                float tg = ftanh(gg);
                c_own = sf*c_own + si*tg;
                h_own = so*ftanh(c_own);
                hbuf[(t + 1) & 1][o] = h_own;
                __hip_atomic_store(&hout[t*HID + o], h_own,
                                   __ATOMIC_RELAXED, __HIP_MEMORY_SCOPE_AGENT);
            }

            // B1: ingemm slice tc (k in [tc*16, tc*16+16)) for chunk c+1
            if (l > 0 && have_next) {
                #pragma unroll
                for (int t2 = 0; t2 < CH; t2++) {
                    const float4* xp = (const float4*)(&xsn[t2*HID + tc*16]);
                    float4 x0 = xp[0], x1 = xp[1], x2 = xp[2], x3 = xp[3];
                    accA[t2] += wva0.x*x0.x + wva0.y*x0.y + wva0.z*x0.z + wva0.w*x0.w
                              + wva1.x*x1.x + wva1.y*x1.y + wva1.z*x1.z + wva1.w*x1.w
                              + wva2.x*x2.x + wva2.y*x2.y + wva2.z*x2.z + wva2.w*x2.w
                              + wva3.x*x3.x + wva3.y*x3.y + wva3.z*x3.z + wva3.w*x3.w;
                    accB[t2] += wvb0.x*x0.x + wvb0.y*x0.y + wvb0.z*x0.z + wvb0.w*x0.w
                              + wvb1.x*x1.x + wvb1.y*x1.y + wvb1.z*x1.z + wvb1.w*x1.w
                              + wvb2.x*x2.x + wvb2.y*x2.y + wvb2.z*x2.z + wvb2.w*x2.w
                              + wvb3.x*x3.x + wvb3.y*x3.y + wvb3.z*x3.z + wvb3.w*x3.w;
                }
                // next slice's weights (wraps to slice 0 for next chunk)
                const int ns = (tc + 1) & 7;
                wva0 = wrA[ns*4+0]; wva1 = wrA[ns*4+1]; wva2 = wrA[ns*4+2]; wva3 = wrA[ns*4+3];
                wvb0 = wrB[ns*4+0]; wvb1 = wrB[ns*4+1]; wvb2 = wrB[ns*4+2]; wvb3 = wrB[ns*4+3];
                if (tc == CH - 1) {
                    #pragma unroll
                    for (int t2 = 0; t2 < CH; t2++) {
                        xgn[t2*GATES + tid]       = accA[t2];
                        xgn[t2*GATES + 256 + tid] = accB[t2];
                        accA[t2] = bsA; accB[t2] = bsB;
                    }
                }
            }

            lds_barrier();   // bar2: hbuf[(t+1)&1] (and tc7's xgn) ready
        }

        // chunk end: drain h stores, rotate l0 xg buffer, publish progress
        if (l == 0) {
            __asm__ volatile("s_waitcnt vmcnt(0)" ::: "memory");   // h stores + pf loads done
            if (have_next) {
                float4* d = (float4*)xg[buf ^ 1];
                d[0*256 + tid] = pf0; d[1*256 + tid] = pf1;
                d[2*256 + tid] = pf2; d[3*256 + tid] = pf3;
                buf ^= 1;
            }
            lds_barrier();
            if (tid == 0)
                __hip_atomic_store(&flags[b], (c+1)*CH,
                                   __ATOMIC_RELAXED, __HIP_MEMORY_SCOPE_AGENT);
        } else {
            __asm__ volatile("s_waitcnt vmcnt(0)" ::: "memory");   // h stores done
            lds_barrier();
            if (l < NLAYERS - 1 && tid == 0)
                __hip_atomic_store(&flags[l*BB + b], (c+1)*CH,
                                   __ATOMIC_RELAXED, __HIP_MEMORY_SCOPE_AGENT);
        }
    }
}

// ---------------- K4: final linear ----------------
__global__ void final_lin(const float* __restrict__ ws, const float* __restrict__ Wlin,
                          const float* __restrict__ blin, float* __restrict__ out) {
    const int b = blockIdx.x, l = threadIdx.x;  // 64 threads
    float acc = 0.f;
    #pragma unroll
    for (int u = 0; u < 8; u++) {
        int idx = u*64 + l;
        int layer = idx >> 7, k = idx & 127;
        const float* hs = ws + WS_HSEQ0 + (size_t)layer*HSEQ_SZ;
        acc += hs[((size_t)b*TT + (TT-1))*HID + k] * Wlin[idx];
    }
    #pragma unroll
    for (int d = 1; d < 64; d <<= 1) acc += __shfl_xor(acc, d);
    if (l == 0) out[b] = acc + blin[0];
}

extern "C" void kernel_launch(void* const* d_in, const int* in_sizes, int n_in,
                              void* d_out, int out_size, void* d_ws, size_t ws_size,
                              hipStream_t stream) {
    const float* x    = (const float*)d_in[0];
    const int*   adj  = (const int*)d_in[1];
    const float* W1   = (const float*)d_in[2];
    const float* a1   = (const float*)d_in[3];
    const float* W2   = (const float*)d_in[4];
    const float* a2   = (const float*)d_in[5];
    const float* Wih  = (const float*)d_in[6];
    const float* Whh  = (const float*)d_in[7];
    const float* bih  = (const float*)d_in[8];
    const float* bhh  = (const float*)d_in[9];
    const float* Wlin = (const float*)d_in[10];
    const float* blin = (const float*)d_in[11];
    const int*   site = (const int*)d_in[12];
    float* ws  = (float*)d_ws;
    float* out = (float*)d_out;

    prep1<<<1, 256, 0, stream>>>(W1, a1, W2, a2, bih, bhh, adj, ws);
    prep2<<<FF, 128, 0, stream>>>(W1, W2, ws);
    prep3<<<35, 256, 0, stream>>>(W1, Wih, ws);
    gat_fused<<<dim3(TT, BB), 256, 0, stream>>>(x, adj, ws, ws + WS_XG, site);
    // all 4 layers concurrently, wavefront-pipelined via agent-scope flags
    lstm_pipe<<<dim3(BB, NLAYERS), 256, 0, stream>>>(ws + WS_XG, Wih, Whh, ws);
    final_lin<<<64, 64, 0, stream>>>(ws, Wlin, blin, out);
}